// Round 14
// baseline (3045.430 us; speedup 1.0000x reference)
//
#include <hip/hip_runtime.h>

#define B_  256
#define T_  512
#define F_  64
#define H_  1024
#define TL_ 64

typedef _Float16 half8 __attribute__((ext_vector_type(8)));
typedef float   floatx4 __attribute__((ext_vector_type(4)));
typedef unsigned long long ull;

#define MFMA(a, b, c) __builtin_amdgcn_mfma_f32_16x16x32_f16(a, b, c, 0, 0, 0)

// ws layout (bytes)
#define WF_E   0UL          // W_hh enc fragments: 3*64*32 chunks * 1024B
#define WF_D   6291456UL    // W_hh dec fragments
#define WF_I   12582912UL   // W_ih enc fragments
#define HP     12976128UL   // h planes: [2 parity][fp16 512KB]
#define PSTR   524288UL     // parity stride
#define PB     15073280UL   // fc partials: [2][64 jg][256 rows] f32
#define BARS   15204352UL   // flags: 16 groups x 16 blocks x 64B = 16KB
// h plane (fragment-major fp16): [rg 16][kb 32][lane 64][16B]; slab 32KB/rg;
// block (rg,cb) owns the contiguous 2KB at rg*32768 + cb*2048.
// NOTE: h is stored fp16-only; each element's own recurrence (z*h_old) is
// carried in fp32 registers (hold[]), so storage quantization never
// compounds (round-11 verified: absmax identical to the hi/lo scheme).

// LLC-coherent scalar atomics (sc0 sc1: bypass L1/L2, coherent at IF).
__device__ __forceinline__ void sta8(void* p, ull v) {
  __hip_atomic_store((ull*)p, v, __ATOMIC_RELAXED, __HIP_MEMORY_SCOPE_AGENT);
}
__device__ __forceinline__ float lda4f(const float* p) {
  return __hip_atomic_load(p, __ATOMIC_RELAXED, __HIP_MEMORY_SCOPE_AGENT);
}
__device__ __forceinline__ unsigned lda4u(const unsigned* p) {
  return __hip_atomic_load(p, __ATOMIC_RELAXED, __HIP_MEMORY_SCOPE_AGENT);
}

// ---------------------------------------------------------------------------
// Setup: W fragment conversion (layout unchanged) + zero the flag region.
// B-frag 16x16x32: lane L holds B[k=(L>>4)*8+t][n=L&15] ->
// W[g*H + jg*16 + (L&15)][kb*32 + (L>>4)*8 + t].
// ---------------------------------------------------------------------------
__global__ void gru_setup(const float* __restrict__ WhhE,
                          const float* __restrict__ WhhD,
                          const float* __restrict__ WihE,
                          char* __restrict__ ws) {
  int t = blockIdx.x * 256 + threadIdx.x;
  if (t < 4096) ((unsigned*)(ws + BARS))[t] = 0u;
  const int NW = 3 * 64 * 32 * 4 * 16;
  if (t < 2 * NW) {
    const float* W = (t < NW) ? WhhE : WhhD;
    size_t dst = (t < NW) ? WF_E : WF_D;
    int c = (t < NW) ? t : t - NW;
    int r = c & 15, q = (c >> 4) & 3, kb = (c >> 6) & 31, gj = c >> 11;
    int row = (gj >> 6) * H_ + (gj & 63) * 16 + r;
    const float* src = W + (size_t)row * H_ + kb * 32 + q * 8;
    half8 v;
#pragma unroll
    for (int i = 0; i < 8; ++i) v[i] = (_Float16)src[i];
    *(half8*)(ws + dst + (size_t)c * 16) = v;
  } else if (t < 2 * NW + 3 * 64 * 2 * 4 * 16) {
    int c = t - 2 * NW;
    int r = c & 15, q = (c >> 4) & 3, kc = (c >> 6) & 1, gj = c >> 7;
    int row = (gj >> 6) * H_ + (gj & 63) * 16 + r;
    const float* src = WihE + (size_t)row * F_ + kc * 32 + q * 8;
    half8 v;
#pragma unroll
    for (int i = 0; i < 8; ++i) v[i] = (_Float16)src[i];
    *(half8*)(ws + WF_I + (size_t)c * 16) = v;
  }
}

// ---------------------------------------------------------------------------
// Group barrier, RMW-free: each block stores its epoch to its OWN cacheline
// (16 parallel stores, no LLC same-line RMW serialization -- round-11's
// fetch_add counter serialized 16 RMWs + poll reads on one line). Wave 0
// lanes 0..15 poll the 16 flags in parallel; __ballot converges the wave.
// Visibility: per-thread vmcnt drain at __syncthreads() means all h' stores
// are ACKED at the IF before the flag store issues (rounds 3-11 argument).
// ---------------------------------------------------------------------------
__device__ __forceinline__ void gbar(unsigned* flg, int cb, unsigned bt,
                                     int L, int w) {
  __syncthreads();
  if (w == 0) {
    if (L == 0)
      __hip_atomic_store(&flg[cb * 16], bt, __ATOMIC_RELAXED,
                         __HIP_MEMORY_SCOPE_AGENT);
    unsigned f = bt;
    for (;;) {
      if (L < 16) f = lda4u(&flg[L * 16]);
      if (!__ballot(f < bt)) break;
      __builtin_amdgcn_s_sleep(1);
    }
  }
  __syncthreads();
}

// ---------------------------------------------------------------------------
// Main persistent kernel: 256 blocks x 512 thr (8 waves, 1 block/CU) — the
// round-11 champion, with the RMW-free flag barrier as the only change.
// Block (rg=bx&15, cb=bx>>4): rows [rg*16,+16), h-cols [cb*64,+64).
// Wave w: jp=w&3 (jg=cb*4+jp), kh=w>>2 (K-half); bW = 48 chunks/wave.
// Coherent-fabric staging: 8 MB/step (rounds 4/5/6/11: step time tracks
// staged bytes at ~3.5 TB/s; W-residency and spills proven non-binding).
// ---------------------------------------------------------------------------
__global__ __launch_bounds__(512, 2) void gru_main(
    const float* __restrict__ x,
    const float* __restrict__ bih_e, const float* __restrict__ bhh_e,
    const float* __restrict__ Wih_d,
    const float* __restrict__ bih_d, const float* __restrict__ bhh_d,
    const float* __restrict__ fcW, const float* __restrict__ fcb,
    float* __restrict__ out, char* __restrict__ ws) {

  __shared__ __align__(128) char atile[32768];  // [kb 32][L 64][16B]
  __shared__ float red[4 * 64 * 17];            // kh1 partials [jp][L][17]
  __shared__ __align__(16) char otile[2048];    // h' image (2KB)
  __shared__ float inp_lds[16];

  const int tid = threadIdx.x;
  const int L = tid & 63;
  const int w = tid >> 6;
  const int jp = w & 3;
  const int kh = w >> 2;
  const int bx = blockIdx.x;
  const int rg = bx & 15;
  const int cb = bx >> 4;
  const int r = L & 15;
  const int q = L >> 4;
  const int jg = cb * 4 + jp;
  const int jc = jg * 16 + r;

  unsigned* flg = (unsigned*)(ws + BARS) + (size_t)rg * 256;  // 16 x 64B
  unsigned bt = 0;

  const size_t slab = (size_t)rg * 32768;

  // zero own h'-region of parity 0 (2KB/block)
  if (tid < 256) {
    sta8(ws + HP + slab + (size_t)cb * 2048 + (size_t)tid * 8, 0ull);
  }

  float hold[4] = {0.f, 0.f, 0.f, 0.f};
  const float fcb_s = *fcb;
  const float fcw_l = fcW[jc];

  ++bt;
  gbar(flg, cb, bt, L, w);

  for (int phase = 0; phase < 2; ++phase) {
    // register-resident W_hh B-frags for (jg, kh): [gate][kk].
    half8 bW[48];
    {
      const char* wf = ws + (phase ? WF_D : WF_E);
#pragma unroll
      for (int g = 0; g < 3; ++g)
#pragma unroll
        for (int kk = 0; kk < 16; ++kk)
          bW[g * 16 + kk] = *(const half8*)(
              wf + (size_t)((g * 64 + jg) * 32 + kh * 16 + kk) * 1024 +
              (size_t)L * 16);
#pragma unroll
      for (int i = 0; i < 48; ++i) asm volatile("" : "+v"(bW[i]));
    }
    const float* bih = phase ? bih_d : bih_e;
    const float* bhh = phase ? bhh_d : bhh_e;
    const float b_r  = bih[jc]          + bhh[jc];
    const float b_z  = bih[H_ + jc]     + bhh[H_ + jc];
    const float b_in = bih[2 * H_ + jc];
    const float b_hn = bhh[2 * H_ + jc];
    float wd_r = 0.f, wd_z = 0.f, wd_n = 0.f;
    if (phase) {
      wd_r = Wih_d[jc]; wd_z = Wih_d[H_ + jc]; wd_n = Wih_d[2 * H_ + jc];
    }

    const int nsteps = phase ? TL_ : T_;
    for (int d = 0; d < nsteps; ++d) {
      const int s = phase ? T_ + d : d;

      // ---- stage A slab (32KB) via async global->LDS DMA, LLC-coherent
      //      (aux 17 = sc0|sc1, round-6..11 proven). 32 segs of 1KB; wave w
      //      takes segs w*4..w*4+3; lane L's 16B lands at seg base + L*16. ----
      {
        const char* srcbase = ws + HP + (size_t)(s & 1) * PSTR + slab;
#pragma unroll
        for (int c = 0; c < 4; ++c) {
          const int seg = w * 4 + c;  // 0..31
          const char* src = srcbase + (size_t)seg * 1024 + (size_t)L * 16;
          __builtin_amdgcn_global_load_lds(
              (const __attribute__((address_space(1))) void*)src,
              (__attribute__((address_space(3))) void*)(atile + seg * 1024),
              16, 0, 17);
        }
      }

      // ---- decoder scalar input (overlaps the staging DMA) ----
      if (phase && tid < 16) {
        float sum = 0.f;
        if (d > 0) {
          const float* pb =
              (const float*)(ws + PB) + (size_t)((d + 1) & 1) * 64 * 256;
          int row = rg * 16 + tid;
          float a = fcb_s;
          for (int jj = 0; jj < 64; ++jj) a += lda4f(&pb[jj * 256 + row]);
          sum = a;
          if (cb == 0) out[(size_t)row * TL_ + (d - 1)] = a;
        }
        inp_lds[tid] = sum;
      }
      __syncthreads();  // drains vmcnt -> DMA complete

      floatx4 a0 = {0.f, 0.f, 0.f, 0.f}, a1 = {0.f, 0.f, 0.f, 0.f};
      floatx4 a2 = {0.f, 0.f, 0.f, 0.f}, aI = {0.f, 0.f, 0.f, 0.f};

      // ---- h-GEMM, this wave's K-half (stride-1 ds_read_b128) ----
#pragma unroll
      for (int kk = 0; kk < 16; ++kk) {
        const int kb = kh * 16 + kk;
        half8 ahi = *(const half8*)(atile + kb * 1024 + L * 16);
        a0 = MFMA(ahi, bW[kk], a0);
        a1 = MFMA(ahi, bW[16 + kk], a1);
        a2 = MFMA(ahi, bW[32 + kk], a2);
      }

      // ---- kh1: encoder x-projection + dump partials ----
      if (kh == 1) {
        if (!phase) {
          const float* xp =
              x + ((size_t)(rg * 16 + r) * T_ + s) * F_ + q * 8;
          const char* wfi = ws + WF_I + (size_t)L * 16;  // L1/L2-hot reloads
#pragma unroll
          for (int kc = 0; kc < 2; ++kc) {
            floatx4 x0 = *(const floatx4*)(xp + kc * 32);
            floatx4 x1 = *(const floatx4*)(xp + kc * 32 + 4);
            half8 xa;
#pragma unroll
            for (int i = 0; i < 4; ++i) {
              xa[i] = (_Float16)x0[i];
              xa[4 + i] = (_Float16)x1[i];
            }
            a0 = MFMA(xa, *(const half8*)(wfi +
                     (size_t)((0 * 64 + jg) * 2 + kc) * 1024), a0);
            a1 = MFMA(xa, *(const half8*)(wfi +
                     (size_t)((1 * 64 + jg) * 2 + kc) * 1024), a1);
            aI = MFMA(xa, *(const half8*)(wfi +
                     (size_t)((2 * 64 + jg) * 2 + kc) * 1024), aI);
          }
        }
        float* rd = &red[(jp * 64 + L) * 17];
#pragma unroll
        for (int i = 0; i < 4; ++i) {
          rd[i] = a0[i];
          rd[4 + i] = a1[i];
          rd[8 + i] = a2[i];
        }
        if (!phase) {
#pragma unroll
          for (int i = 0; i < 4; ++i) rd[12 + i] = aI[i];
        }
      }
      __syncthreads();

      // ---- kh0: reduce halves, gate epilogue, h' -> otile ----
      if (kh == 0) {
        const float* rd = &red[(jp * 64 + L) * 17];
        const size_t tbase = (size_t)(jp >> 1) * 1024 +
                             (size_t)((jp & 1) * 2 + (r >> 3)) * 256 +
                             (size_t)(r & 7) * 2;
        float pv[4];
#pragma unroll
        for (int i = 0; i < 4; ++i) {
          float rpre = a0[i] + rd[i] + b_r;
          float zpre = a1[i] + rd[4 + i] + b_z;
          float hn   = a2[i] + rd[8 + i] + b_hn;
          float inn  = b_in + (phase ? 0.f : rd[12 + i]);
          if (phase) {
            float inp = inp_lds[q * 4 + i];
            rpre += inp * wd_r;
            zpre += inp * wd_z;
            inn  += inp * wd_n;
          }
          float rg_ = 1.f / (1.f + __expf(-rpre));
          float zg = 1.f / (1.f + __expf(-zpre));
          float t2 = __expf(-2.f * (inn + rg_ * hn));
          float ng = 2.f / (1.f + t2) - 1.f;  // tanh, safe at +-inf
          float hnew = (1.f - zg) * ng + zg * hold[i];
          hold[i] = hnew;  // fp32 carry
          *(_Float16*)(otile + tbase + (size_t)(q * 4 + i) * 16) =
              (_Float16)hnew;
          pv[i] = hnew * fcw_l;
        }
        if (phase) {
#pragma unroll
          for (int i = 0; i < 4; ++i) {
            float v = pv[i];
            v += __shfl_xor(v, 1);
            v += __shfl_xor(v, 2);
            v += __shfl_xor(v, 4);
            v += __shfl_xor(v, 8);
            if (r == 0) {
              float* pb = (float*)(ws + PB) + (size_t)(d & 1) * 64 * 256;
              __hip_atomic_store(&pb[jg * 256 + (rg * 16 + q * 4 + i)], v,
                                 __ATOMIC_RELAXED, __HIP_MEMORY_SCOPE_AGENT);
            }
          }
        }
      }
      __syncthreads();

      // ---- stream h' (2KB) out: coalesced 8B LLC stores ----
      if (tid < 256) {
        ull v = *(const ull*)(otile + (size_t)tid * 8);
        sta8(ws + HP + (size_t)((s + 1) & 1) * PSTR + slab +
                 (size_t)cb * 2048 + (size_t)tid * 8,
             v);
      }

      ++bt;
      gbar(flg, cb, bt, L, w);
    }
  }

  // ---- final output column t = TL-1 ----
  if (cb == 0 && tid < 16) {
    const float* pb =
        (const float*)(ws + PB) + (size_t)((TL_ - 1) & 1) * 64 * 256;
    int row = rg * 16 + tid;
    float a = fcb_s;
    for (int jj = 0; jj < 64; ++jj) a += lda4f(&pb[jj * 256 + row]);
    out[(size_t)row * TL_ + (TL_ - 1)] = a;
  }
}

// ---------------------------------------------------------------------------
extern "C" void kernel_launch(void* const* d_in, const int* in_sizes, int n_in,
                              void* d_out, int out_size, void* d_ws,
                              size_t ws_size, hipStream_t stream) {
  const float* x     = (const float*)d_in[0];
  const float* WihE  = (const float*)d_in[1];
  const float* WhhE  = (const float*)d_in[2];
  const float* bihE  = (const float*)d_in[3];
  const float* bhhE  = (const float*)d_in[4];
  const float* WihD  = (const float*)d_in[5];
  const float* WhhD  = (const float*)d_in[6];
  const float* bihD  = (const float*)d_in[7];
  const float* bhhD  = (const float*)d_in[8];
  const float* fcW   = (const float*)d_in[9];
  const float* fcb   = (const float*)d_in[10];
  float* outp = (float*)d_out;
  char* ws = (char*)d_ws;

  gru_setup<<<3168, 256, 0, stream>>>(WhhE, WhhD, WihE, ws);

  gru_main<<<dim3(256), dim3(512), 0, stream>>>(
      x, bihE, bhhE, WihD, bihD, bhhD, fcW, fcb, outp, ws);
}